// Round 20
// baseline (2143.714 us; speedup 1.0000x reference)
//
#include <hip/hip_runtime.h>
#include <hip/hip_bf16.h>

#define B_ 2
#define T_ 512
#define D_ 512
#define H_ 8
#define L_ 6
#define F_ 2048
#define V_ 32000
#define BT_ (B_ * T_)
#define HD_ (H_ * D_)
#define BH_ (B_ * H_)

typedef __attribute__((ext_vector_type(8))) short short8;
typedef __attribute__((ext_vector_type(4))) short short4v;
typedef __attribute__((ext_vector_type(4))) float f32x4;

__device__ __forceinline__ short f2b(float f) {
  __hip_bfloat16 h = __float2bfloat16(f);
  short u; __builtin_memcpy(&u, &h, 2); return u;
}
__device__ __forceinline__ float b2f16(short u) {
  return __uint_as_float(((unsigned)(unsigned short)u) << 16);
}
__device__ __forceinline__ void store_c(float* p, float v) { *p = v; }
__device__ __forceinline__ void store_c(short* p, float v) { *p = f2b(v); }

// ------- embedding * sqrt(D) + sinusoidal PE, both streams in one dispatch (y-dim) -------
__global__ __launch_bounds__(256) void embed_kernel(
    const int* __restrict__ tokx, const int* __restrict__ toky,
    const float* __restrict__ emb0, const float* __restrict__ emb1,
    float* __restrict__ out0, float* __restrict__ out1,
    short* __restrict__ o160, short* __restrict__ o161)
{
  const int which = blockIdx.y;
  const int row = blockIdx.x;
  const int t = row & (T_ - 1);
  const int token = which ? toky[row] : tokx[row];
  const float* e = (which ? emb1 : emb0) + (size_t)token * D_;
  float* o = (which ? out1 : out0) + (size_t)row * D_;
  short* o16 = (which ? o161 : o160) + (size_t)row * D_;
  const float scale = sqrtf((float)D_);
  const float nl = -logf(10000.0f);
  for (int d = threadIdx.x; d < D_; d += 256) {
    int i = d >> 1;
    float wl = expf(nl * (2.0f * (float)i) / (float)D_);
    float ang = (float)t * wl;
    float pe = (d & 1) ? cosf(ang) : sinf(ang);
    float v = e[d] * scale + pe;
    o[d] = v; o16[d] = f2b(v);
  }
}

// ------- weight prep: up to 3 tensor groups, f32 [K][N] -> bf16 [N][K], z-partitioned ----
// Block covers 64 n-rows x 256 k: 4 coalesced f32 read sub-tiles -> packed-dword bf16
// LDS out-tile -> flush with 512B-contiguous rows. K must be a multiple of 256.
__global__ __launch_bounds__(256) void wconv3_kernel(
    const float* __restrict__ s0, const float* __restrict__ s1, const float* __restrict__ s2,
    short* __restrict__ d0, short* __restrict__ d1, short* __restrict__ d2,
    int K, int N, int zper)
{
  __shared__ float tile[64][65];
  __shared__ unsigned outt[64][129];
  const int z = blockIdx.z;
  const int grp = z / zper, zi = z - grp * zper;
  const long mstride = (long)K * N;
  const float* src = (grp == 0 ? s0 : grp == 1 ? s1 : s2) + (long)zi * mstride;
  short* dst = (grp == 0 ? d0 : grp == 1 ? d1 : d2) + (long)zi * mstride;
  const int kq0 = blockIdx.y * 256, n0 = blockIdx.x * 64;
  const int tid = threadIdx.x;
  const int rr = tid >> 4, c4 = (tid & 15) << 2;

  for (int sub = 0; sub < 4; ++sub) {
    const int kb = kq0 + sub * 64;
#pragma unroll
    for (int i = 0; i < 4; ++i) {
      float4 v = *(const float4*)(src + (long)(kb + rr + i * 16) * N + n0 + c4);
      tile[rr + i * 16][c4 + 0] = v.x;
      tile[rr + i * 16][c4 + 1] = v.y;
      tile[rr + i * 16][c4 + 2] = v.z;
      tile[rr + i * 16][c4 + 3] = v.w;
    }
    __syncthreads();
    // convert: pack 2 k per dword; LDS reads stride-1, writes stride-129 (conflict-free)
#pragma unroll
    for (int i = 0; i < 8; ++i) {
      const int idx = i * 256 + tid;
      const int n = idx & 63, kp = idx >> 6;    // kp 0..31
      const unsigned lo = (unsigned)(unsigned short)f2b(tile[2 * kp][n]);
      const unsigned hi = (unsigned)(unsigned short)f2b(tile[2 * kp + 1][n]);
      outt[n][sub * 32 + kp] = lo | (hi << 16);
    }
    __syncthreads();
  }
  // flush: 64 rows x 256 k, 512B contiguous per row, 32 lanes stream 512B
#pragma unroll
  for (int i = 0; i < 8; ++i) {
    const int idx = i * 256 + tid;
    const int row = idx >> 5, c8 = idx & 31;
    const unsigned u0 = outt[row][c8 * 4 + 0], u1 = outt[row][c8 * 4 + 1];
    const unsigned u2 = outt[row][c8 * 4 + 2], u3 = outt[row][c8 * 4 + 3];
    short8 o;
    o[0] = (short)(u0 & 0xffff); o[1] = (short)(u0 >> 16);
    o[2] = (short)(u1 & 0xffff); o[3] = (short)(u1 >> 16);
    o[4] = (short)(u2 & 0xffff); o[5] = (short)(u2 >> 16);
    o[6] = (short)(u3 & 0xffff); o[7] = (short)(u3 >> 16);
    *(short8*)(dst + (long)(n0 + row) * K + kq0 + c8 * 8) = o;
  }
}

// ---------------- generic MFMA GEMM (r6 structure: single-buffer + reg prefetch) --------
template<bool BTM, typename OutT, int BM>
__global__ __launch_bounds__(256, BM == 64 ? 4 : 3) void mfma_gemm(
    const short* __restrict__ A, long lda, long a_hi, long a_lo, int a_once,
    const void* __restrict__ Bv, long ldb, long b_hi, long b_lo,
    OutT* __restrict__ C, long ldc, long c_hi, long c_lo, long pstride,
    short* __restrict__ Ct, int trans_hh, int relu, int cskip, int cklim,
    int K, int nh, int ksplit, float scale,
    const float* __restrict__ bias, long bias_stride)
{
  constexpr int SA = BM + 1;
  constexpr int AU = BM / 32;
  constexpr int WRN = (BM == 128) ? 2 : 1;
  constexpr int WN  = (BM == 128) ? 64 : 32;
  constexpr int NR  = WN / 16;
  __shared__ short8 As8[8 * SA];
  __shared__ short8 Bs8[8 * 129];
  const int tid = threadIdx.x;
  const int bh = blockIdx.z / ksplit;
  const int kz = blockIdx.z - bh * ksplit;
  const int bb = bh / nh, hh = bh - bb * nh;
  const long a_off = a_once ? (hh >= 1 ? a_lo : 0) : (long)hh * a_lo;
  const short* Ab = A + (long)bb * a_hi + a_off;
  const short* Bbs = (const short*)Bv + (long)bb * b_hi + (long)hh * b_lo;
  const float* Bbf = (const float*)Bv + (long)bb * b_hi + (long)hh * b_lo;
  OutT* Cb = C + (long)bb * c_hi + (long)hh * c_lo + (long)kz * pstride;

  const int gx = gridDim.x, gy = gridDim.y;
  const int nwg = gx * gy;
  int lin = blockIdx.y * gx + blockIdx.x;
  {
    const int xcd = lin & 7, idx = lin >> 3;
    const int q = nwg >> 3, r = nwg & 7;
    lin = (xcd < r ? xcd * (q + 1) : r * (q + 1) + (xcd - r) * q) + idx;
  }
  const int bn = (lin / gy) * 128;
  const int bm = (lin % gy) * BM;
  if (cskip && bn > bm + BM - 1) return;   // causal upper triangle: S never read

  const int klen = K / ksplit, kbase = kz * klen;
  const int lane = tid & 63, wid = tid >> 6;
  const int wr = (WRN == 2) ? (wid >> 1) : 0;
  const int wc = (WRN == 2) ? (wid & 1) : wid;
  const int lg = lane >> 4, r16 = lane & 15;

  int arow[AU], acol[AU];
#pragma unroll
  for (int u = 0; u < AU; ++u) { int o = u * 256 + tid; arow[u] = o >> 3; acol[u] = o & 7; }
  int brow[4], bcol[4];
#pragma unroll
  for (int u = 0; u < 4; ++u) { int o = u * 256 + tid; brow[u] = o >> 3; bcol[u] = o & 7; }
  const int ncol = tid & 127, nsh = tid >> 7;

  short8 pa[AU];
  short8 pbt[4];
  float  pbn[4][8];

  auto load = [&](int k0) {
#pragma unroll
    for (int u = 0; u < AU; ++u)
      pa[u] = *(const short8*)(Ab + (long)(bm + arow[u]) * lda + (k0 + acol[u] * 8));
    if constexpr (BTM) {
#pragma unroll
      for (int u = 0; u < 4; ++u)
        pbt[u] = *(const short8*)(Bbs + (long)(bn + brow[u]) * ldb + (k0 + bcol[u] * 8));
    } else {
      const float* s = Bbf + (long)(k0 + nsh * 32) * ldb + (bn + ncol);
#pragma unroll
      for (int i = 0; i < 4; ++i)
#pragma unroll
        for (int j = 0; j < 8; ++j)
          pbn[i][j] = s[(long)(i * 8 + j) * ldb];
    }
  };
  auto stage = [&]() {
#pragma unroll
    for (int u = 0; u < AU; ++u) As8[acol[u] * SA + arow[u]] = pa[u];
    if constexpr (BTM) {
#pragma unroll
      for (int u = 0; u < 4; ++u) Bs8[bcol[u] * 129 + brow[u]] = pbt[u];
    } else {
#pragma unroll
      for (int i = 0; i < 4; ++i) {
        short8 v;
#pragma unroll
        for (int j = 0; j < 8; ++j) v[j] = f2b(pbn[i][j]);
        Bs8[(nsh * 4 + i) * 129 + ncol] = v;
      }
    }
  };

  f32x4 acc[4][NR] = {};
  auto domfma = [&]() {
#pragma unroll
    for (int kb = 0; kb < 2; ++kb) {
      const int cha = (kb * 4 + lg) * SA;
      const int chb = (kb * 4 + lg) * 129;
      short8 a0 = As8[cha + wr * 64 +  0 + r16];
      short8 a1 = As8[cha + wr * 64 + 16 + r16];
      short8 a2 = As8[cha + wr * 64 + 32 + r16];
      short8 a3 = As8[cha + wr * 64 + 48 + r16];
#pragma unroll
      for (int n = 0; n < NR; ++n) {
        short8 bfr = Bs8[chb + wc * WN + n * 16 + r16];
        acc[0][n] = __builtin_amdgcn_mfma_f32_16x16x32_bf16(a0, bfr, acc[0][n], 0, 0, 0);
        acc[1][n] = __builtin_amdgcn_mfma_f32_16x16x32_bf16(a1, bfr, acc[1][n], 0, 0, 0);
        acc[2][n] = __builtin_amdgcn_mfma_f32_16x16x32_bf16(a2, bfr, acc[2][n], 0, 0, 0);
        acc[3][n] = __builtin_amdgcn_mfma_f32_16x16x32_bf16(a3, bfr, acc[3][n], 0, 0, 0);
      }
    }
  };

  int nsteps = klen >> 6;
  if (cklim) { const int lim = (bm >> 6) + 1; if (lim < nsteps) nsteps = lim; }
  load(kbase);
  stage();
  __syncthreads();
  for (int t = 0; t < nsteps; ++t) {
    const bool more = (t + 1 < nsteps);
    if (more) load(kbase + (t + 1) * 64);
    domfma();
    if (more) { __syncthreads(); stage(); __syncthreads(); }
  }

  const float* bp = bias ? bias + (long)hh * bias_stride : nullptr;
  if (hh == trans_hh) {
#pragma unroll
    for (int m = 0; m < 4; ++m)
#pragma unroll
      for (int n = 0; n < NR; ++n) {
        const int col = bn + wc * WN + n * 16 + r16;
        const float badd = bp ? bp[col] : 0.0f;
        short4v sv;
#pragma unroll
        for (int rr = 0; rr < 4; ++rr) sv[rr] = f2b(acc[m][n][rr] * scale + badd);
        *(short4v*)(Ct + (long)col * BT_ + (bm + wr * 64 + m * 16 + lg * 4)) = sv;
      }
  } else {
#pragma unroll
    for (int m = 0; m < 4; ++m)
#pragma unroll
      for (int rr = 0; rr < 4; ++rr) {
        const int row = bm + wr * 64 + m * 16 + lg * 4 + rr;
        OutT* crow = Cb + (long)row * ldc + bn + wc * WN + r16;
#pragma unroll
        for (int n = 0; n < NR; ++n) {
          float v = acc[m][n][rr] * scale;
          if (bp) v += bp[bn + wc * WN + n * 16 + r16];
          if (relu) v = fmaxf(v, 0.0f);
          store_c(&crow[n * 16], v);
        }
      }
  }
}

// ---- fused: x = resid + bias + sum_z partial; resid(f32) = LN(x)*g+b; + bf16 copy ----
__global__ __launch_bounds__(256) void reduce_ln_kernel(
    const float* __restrict__ P, long pstride, int ks,
    const float* __restrict__ bias, float* __restrict__ hbuf, short* __restrict__ h16,
    const float* __restrict__ gam, const float* __restrict__ bet)
{
  __shared__ float red[256];
  const int row = blockIdx.x, tid = threadIdx.x;
  const long base = (long)row * D_;
  float s0 = hbuf[base + tid] + bias[tid];
  float s1 = hbuf[base + tid + 256] + bias[tid + 256];
  for (int z = 0; z < ks; ++z) {
    s0 += P[(long)z * pstride + base + tid];
    s1 += P[(long)z * pstride + base + tid + 256];
  }
  red[tid] = s0 + s1; __syncthreads();
  for (int o = 128; o > 0; o >>= 1) { if (tid < o) red[tid] += red[tid + o]; __syncthreads(); }
  const float mean = red[0] * (1.0f / D_); __syncthreads();
  const float d0 = s0 - mean, d1 = s1 - mean;
  red[tid] = d0 * d0 + d1 * d1; __syncthreads();
  for (int o = 128; o > 0; o >>= 1) { if (tid < o) red[tid] += red[tid + o]; __syncthreads(); }
  const float inv = rsqrtf(red[0] * (1.0f / D_) + 1e-6f);
  const float v0 = d0 * inv * gam[tid] + bet[tid];
  const float v1 = d1 * inv * gam[tid + 256] + bet[tid + 256];
  hbuf[base + tid] = v0;       h16[base + tid] = f2b(v0);
  hbuf[base + tid + 256] = v1; h16[base + tid + 256] = f2b(v1);
}

// ------- wave-per-row softmax (bf16 S in, bf16 P out); no barriers, no LDS -------
__global__ __launch_bounds__(256) void softmax_kernel(
    const short* __restrict__ S, short* __restrict__ P, int causal)
{
  const int wid = threadIdx.x >> 6, lane = threadIdx.x & 63;
  const int q = blockIdx.x * 4 + wid;
  const int bh = blockIdx.y;
  const short* row = S + ((size_t)bh * T_ + q) * T_;
  short* prow = P + ((size_t)bh * T_ + q) * T_;
  const int n = causal ? (q + 1) : T_;
  const int base = lane * 8;
  short8 sv = *(const short8*)(row + base);
  float vals[8];
#pragma unroll
  for (int j = 0; j < 8; ++j) vals[j] = b2f16(sv[j]);
  float mx = -3.0e38f;
#pragma unroll
  for (int j = 0; j < 8; ++j)
    if (base + j < n) mx = fmaxf(mx, vals[j]);
  mx = fmaxf(mx, __shfl_xor(mx, 1));
  mx = fmaxf(mx, __shfl_xor(mx, 2));
  mx = fmaxf(mx, __shfl_xor(mx, 4));
  mx = fmaxf(mx, __shfl_xor(mx, 8));
  mx = fmaxf(mx, __shfl_xor(mx, 16));
  mx = fmaxf(mx, __shfl_xor(mx, 32));
  float e[8];
  float sm = 0.0f;
#pragma unroll
  for (int j = 0; j < 8; ++j) {
    e[j] = (base + j < n) ? expf(vals[j] - mx) : 0.0f;
    sm += e[j];
  }
  sm += __shfl_xor(sm, 1);
  sm += __shfl_xor(sm, 2);
  sm += __shfl_xor(sm, 4);
  sm += __shfl_xor(sm, 8);
  sm += __shfl_xor(sm, 16);
  sm += __shfl_xor(sm, 32);
  const float inv = 1.0f / sm;
  short8 ov;
#pragma unroll
  for (int j = 0; j < 8; ++j) ov[j] = f2b(e[j] * inv);
  *(short8*)(prow + base) = ov;
}

extern "C" void kernel_launch(void* const* d_in, const int* in_sizes, int n_in,
                              void* d_out, int out_size, void* d_ws, size_t ws_size,
                              hipStream_t stream)
{
  const int*   x         = (const int*)d_in[0];
  const int*   y         = (const int*)d_in[1];
  const float* enc_emb   = (const float*)d_in[2];
  const float* dec_emb   = (const float*)d_in[3];
  const float* enc_qkv_w = (const float*)d_in[4];
  const float* enc_qkv_b = (const float*)d_in[5];
  const float* enc_out_w = (const float*)d_in[6];
  const float* enc_out_b = (const float*)d_in[7];
  const float* enc_ln1_g = (const float*)d_in[8];
  const float* enc_ln1_b = (const float*)d_in[9];
  const float* enc_ff_w1 = (const float*)d_in[10];
  const float* enc_ff_b1 = (const float*)d_in[11];
  const float* enc_ff_w2 = (const float*)d_in[12];
  const float* enc_ff_b2 = (const float*)d_in[13];
  const float* enc_ln2_g = (const float*)d_in[14];
  const float* enc_ln2_b = (const float*)d_in[15];
  const float* dec_sa_qkv_w = (const float*)d_in[16];
  const float* dec_sa_qkv_b = (const float*)d_in[17];
  const float* dec_sa_out_w = (const float*)d_in[18];
  const float* dec_sa_out_b = (const float*)d_in[19];
  const float* dec_ln1_g = (const float*)d_in[20];
  const float* dec_ln1_b = (const float*)d_in[21];
  const float* dec_ca_qkv_w = (const float*)d_in[22];
  const float* dec_ca_qkv_b = (const float*)d_in[23];
  const float* dec_ca_out_w = (const float*)d_in[24];
  const float* dec_ca_out_b = (const float*)d_in[25];
  const float* dec_ln2_g = (const float*)d_in[26];
  const float* dec_ln2_b = (const float*)d_in[27];
  const float* dec_ff_w1 = (const float*)d_in[28];
  const float* dec_ff_b1 = (const float*)d_in[29];
  const float* dec_ff_w2 = (const float*)d_in[30];
  const float* dec_ff_b2 = (const float*)d_in[31];
  const float* dec_ln3_g = (const float*)d_in[32];
  const float* dec_ln3_b = (const float*)d_in[33];
  const float* head_w    = (const float*)d_in[34];
  const float* head_b    = (const float*)d_in[35];
  float* out = (float*)d_out;

  // ---- workspace carve-up ----
  char* wsb = (char*)d_ws;
  size_t off = 0;
  auto carve = [&](size_t bytes) { char* p = wsb + off; off += (bytes + 255) & ~255ull; return p; };
  float* h    = (float*)carve((size_t)BT_ * D_ * 4);
  float* dd   = (float*)carve((size_t)BT_ * D_ * 4);
  short* hb16 = (short*)carve((size_t)BT_ * D_ * 2);
  short* db16 = (short*)carve((size_t)BT_ * D_ * 2);
  short* Qb   = (short*)carve((size_t)BT_ * HD_ * 2);
  short* Kb   = (short*)carve((size_t)BT_ * HD_ * 2);
  short* Vt   = (short*)carve((size_t)HD_ * BT_ * 2);
  float* Sb   = (float*)carve((size_t)BH_ * T_ * T_ * 4);  // split-K partials; S16 aliases head
  short* Pb   = (short*)carve((size_t)BH_ * T_ * T_ * 2);
  short* S16  = (short*)Sb;   // bf16 scores (dead before partials are written)
  short* Ob   = Qb;   // Q dead after QK^T
  short* mid  = Qb;   // attn buffers dead during FFN

  // converted-weight region (bf16 [N][K]); enabled only if workspace fits
  const size_t QKVG = (size_t)L_ * 3 * D_ * HD_;
  const size_t OUTG = (size_t)L_ * HD_ * D_;
  const size_t FFG  = (size_t)L_ * D_ * F_;
  const size_t HEADG = (size_t)D_ * V_;
  const size_t conv_bytes = (3 * QKVG + 3 * OUTG + 2 * FFG + 2 * FFG + HEADG) * 2 + 4096;
  const bool WBT = (ws_size >= off + conv_bytes);
  short *Weq = nullptr, *Wdsq = nullptr, *Wdcq = nullptr;
  short *Weo = nullptr, *Wdso = nullptr, *Wdco = nullptr;
  short *Wef1 = nullptr, *Wef2 = nullptr, *Wdf1 = nullptr, *Wdf2 = nullptr, *Whd = nullptr;
  if (WBT) {
    Weq  = (short*)carve(QKVG * 2);  Wdsq = (short*)carve(QKVG * 2);  Wdcq = (short*)carve(QKVG * 2);
    Weo  = (short*)carve(OUTG * 2);  Wdso = (short*)carve(OUTG * 2);  Wdco = (short*)carve(OUTG * 2);
    Wef1 = (short*)carve(FFG * 2);   Wef2 = (short*)carve(FFG * 2);
    Wdf1 = (short*)carve(FFG * 2);   Wdf2 = (short*)carve(FFG * 2);
    Whd  = (short*)carve(HEADG * 2);
  }

  dim3 blk(256);
  const long TT  = (long)T_ * T_;
  const long THD = (long)T_ * HD_;
  const long WQKV = (long)D_ * HD_;

  if (WBT) {
    // merged weight conversions: 5 dispatches; block = 64n x 256k
    wconv3_kernel<<<dim3(HD_/64, D_/256, 3 * 3 * L_), blk, 0, stream>>>(
        enc_qkv_w, dec_sa_qkv_w, dec_ca_qkv_w, Weq, Wdsq, Wdcq, D_, HD_, 3 * L_);
    wconv3_kernel<<<dim3(D_/64, HD_/256, 3 * L_), blk, 0, stream>>>(
        enc_out_w, dec_sa_out_w, dec_ca_out_w, Weo, Wdso, Wdco, HD_, D_, L_);
    wconv3_kernel<<<dim3(F_/64, D_/256, 2 * L_), blk, 0, stream>>>(
        enc_ff_w1, dec_ff_w1, dec_ff_w1, Wef1, Wdf1, Wdf1, D_, F_, L_);
    wconv3_kernel<<<dim3(D_/64, F_/256, 2 * L_), blk, 0, stream>>>(
        enc_ff_w2, dec_ff_w2, dec_ff_w2, Wef2, Wdf2, Wdf2, F_, D_, L_);
    wconv3_kernel<<<dim3(V_/64, D_/256, 1), blk, 0, stream>>>(
        head_w, head_w, head_w, Whd, Whd, Whd, D_, V_, 1);
  }

  auto gemm = [&](bool bt, bool of32, bool bm64, int relu, int cskip, int cklim,
                  const short* A, long lda, long a_hi, long a_lo, int a_once,
                  const void* Bp, long ldb, long b_hi, long b_lo,
                  void* Cp, long ldc, long c_hi, long c_lo, long pstride,
                  short* Ct, int trans_hh,
                  int M, int N, int K, int batch, int nh, int ksplit,
                  float scale, const float* bias, long bstride) {
    dim3 grd(N / 128, M / (bm64 ? 64 : 128), batch * ksplit);
    if (bm64) {
      if (bt) {
        if (of32) mfma_gemm<true , float, 64><<<grd, blk, 0, stream>>>(A, lda, a_hi, a_lo, a_once, Bp, ldb, b_hi, b_lo,
            (float*)Cp, ldc, c_hi, c_lo, pstride, Ct, trans_hh, relu, cskip, cklim, K, nh, ksplit, scale, bias, bstride);
        else      mfma_gemm<true , short, 64><<<grd, blk, 0, stream>>>(A, lda, a_hi, a_lo, a_once, Bp, ldb, b_hi, b_lo,
            (short*)Cp, ldc, c_hi, c_lo, pstride, Ct, trans_hh, relu, cskip, cklim, K, nh, ksplit, scale, bias, bstride);
      } else {
        if (of32) mfma_gemm<false, float, 64><<<grd, blk, 0, stream>>>(A, lda, a_hi, a_lo, a_once, Bp, ldb, b_hi, b_lo,
            (float*)Cp, ldc, c_hi, c_lo, pstride, Ct, trans_hh, relu, cskip, cklim, K, nh, ksplit, scale, bias, bstride);
        else      mfma_gemm<false, short, 64><<<grd, blk, 0, stream>>>(A, lda, a_hi, a_lo, a_once, Bp, ldb, b_hi, b_lo,
            (short*)Cp, ldc, c_hi, c_lo, pstride, Ct, trans_hh, relu, cskip, cklim, K, nh, ksplit, scale, bias, bstride);
      }
    } else {
      if (bt) {
        if (of32) mfma_gemm<true , float, 128><<<grd, blk, 0, stream>>>(A, lda, a_hi, a_lo, a_once, Bp, ldb, b_hi, b_lo,
            (float*)Cp, ldc, c_hi, c_lo, pstride, Ct, trans_hh, relu, cskip, cklim, K, nh, ksplit, scale, bias, bstride);
        else      mfma_gemm<true , short, 128><<<grd, blk, 0, stream>>>(A, lda, a_hi, a_lo, a_once, Bp, ldb, b_hi, b_lo,
            (short*)Cp, ldc, c_hi, c_lo, pstride, Ct, trans_hh, relu, cskip, cklim, K, nh, ksplit, scale, bias, bstride);
      } else {
        if (of32) mfma_gemm<false, float, 128><<<grd, blk, 0, stream>>>(A, lda, a_hi, a_lo, a_once, Bp, ldb, b_hi, b_lo,
            (float*)Cp, ldc, c_hi, c_lo, pstride, Ct, trans_hh, relu, cskip, cklim, K, nh, ksplit, scale, bias, bstride);
        else      mfma_gemm<false, short, 128><<<grd, blk, 0, stream>>>(A, lda, a_hi, a_lo, a_once, Bp, ldb, b_hi, b_lo,
            (short*)Cp, ldc, c_hi, c_lo, pstride, Ct, trans_hh, relu, cskip, cklim, K, nh, ksplit, scale, bias, bstride);
      }
    }
  };

  const int KS = 4;   // split-K for out-proj / FF2

  auto attention = [&](const short* qsrc, const short* kvsrc,
                       const float* qkvw, const short* qkvw16, const float* qkvb,
                       const float* ow, const short* ow16, const float* ob,
                       float* resid, short* resid16, int causal,
                       const float* lng, const float* lnb) {
    // fused Q,K,V (z=3, BM=128); hh=0->Qb, hh=1->Kb, hh=2->Vt^T
    if (WBT)
      gemm(true, false, false, 0, 0, 0, qsrc, D_, 0, (long)(kvsrc - qsrc), 1,
           qkvw16, D_, 0, WQKV,
           Qb, HD_, 0, (long)(Kb - Qb), 0, Vt, 2,
           BT_, HD_, D_, 3, 3, 1, 1.0f, qkvb, HD_);
    else
      gemm(false, false, false, 0, 0, 0, qsrc, D_, 0, (long)(kvsrc - qsrc), 1,
           qkvw, HD_, 0, WQKV,
           Qb, HD_, 0, (long)(Kb - Qb), 0, Vt, 2,
           BT_, HD_, D_, 3, 3, 1, 1.0f, qkvb, HD_);
    // S(bf16) = Q K^T / sqrt(D); causal skips upper-triangle blocks
    gemm(true, false, true, 0, causal, 0, Qb, HD_, THD, D_, 0, Kb, HD_, THD, D_,
         S16, T_, (long)H_ * TT, TT, 0, nullptr, -1,
         T_, T_, D_, BH_, H_, 1, 0.044194173824159216f, nullptr, 0);
    softmax_kernel<<<dim3(T_ / 4, BH_), blk, 0, stream>>>(S16, Pb, causal);
    // O = P V (B = V^T); causal limits K-steps per row-block
    gemm(true, false, true, 0, 0, causal, Pb, T_, (long)H_ * TT, TT, 0,
         Vt, BT_, T_, (long)D_ * BT_,
         Ob, HD_, THD, D_, 0, nullptr, -1,
         T_, D_, T_, BH_, H_, 1, 1.0f, nullptr, 0);
    // out-projection split-K -> f32 partials in Sb; fused reduce+resid+LN
    if (WBT)
      gemm(true, true, true, 0, 0, 0, Ob, HD_, 0, 0, 0, ow16, HD_, 0, 0,
           Sb, D_, 0, 0, (long)BT_ * D_, nullptr, -1,
           BT_, D_, HD_, 1, 1, KS, 1.0f, nullptr, 0);
    else
      gemm(false, true, true, 0, 0, 0, Ob, HD_, 0, 0, 0, ow, D_, 0, 0,
           Sb, D_, 0, 0, (long)BT_ * D_, nullptr, -1,
           BT_, D_, HD_, 1, 1, KS, 1.0f, nullptr, 0);
    reduce_ln_kernel<<<dim3(BT_), blk, 0, stream>>>(
        Sb, (long)BT_ * D_, KS, ob, resid, resid16, lng, lnb);
  };

  auto ffn = [&](float* resid, short* resid16,
                 const float* w1, const short* w116, const float* b1,
                 const float* w2, const short* w216, const float* b2,
                 const float* lng, const float* lnb) {
    if (WBT)
      gemm(true, false, true, 1, 0, 0, resid16, D_, 0, 0, 0, w116, D_, 0, 0,
           mid, F_, 0, 0, 0, nullptr, -1,
           BT_, F_, D_, 1, 1, 1, 1.0f, b1, 0);
    else
      gemm(false, false, true, 1, 0, 0, resid16, D_, 0, 0, 0, w1, F_, 0, 0,
           mid, F_, 0, 0, 0, nullptr, -1,
           BT_, F_, D_, 1, 1, 1, 1.0f, b1, 0);
    if (WBT)
      gemm(true, true, true, 0, 0, 0, mid, F_, 0, 0, 0, w216, F_, 0, 0,
           Sb, D_, 0, 0, (long)BT_ * D_, nullptr, -1,
           BT_, D_, F_, 1, 1, KS, 1.0f, nullptr, 0);
    else
      gemm(false, true, true, 0, 0, 0, mid, F_, 0, 0, 0, w2, D_, 0, 0,
           Sb, D_, 0, 0, (long)BT_ * D_, nullptr, -1,
           BT_, D_, F_, 1, 1, KS, 1.0f, nullptr, 0);
    reduce_ln_kernel<<<dim3(BT_), blk, 0, stream>>>(
        Sb, (long)BT_ * D_, KS, b2, resid, resid16, lng, lnb);
  };

  // ---------------- embeddings (both streams, one dispatch) ----------------
  embed_kernel<<<dim3(BT_, 2), blk, 0, stream>>>(x, y, enc_emb, dec_emb, h, dd, hb16, db16);

  // ---------------- encoder ----------------
  for (int i = 0; i < L_; ++i) {
    attention(hb16, hb16,
              enc_qkv_w + (size_t)i * 3 * WQKV, WBT ? Weq + (size_t)i * 3 * WQKV : nullptr,
              enc_qkv_b + (size_t)i * 3 * HD_,
              enc_out_w + (size_t)i * HD_ * D_, WBT ? Weo + (size_t)i * HD_ * D_ : nullptr,
              enc_out_b + (size_t)i * D_,
              h, hb16, 0, enc_ln1_g + (size_t)i * D_, enc_ln1_b + (size_t)i * D_);
    ffn(h, hb16,
        enc_ff_w1 + (size_t)i * D_ * F_, WBT ? Wef1 + (size_t)i * D_ * F_ : nullptr,
        enc_ff_b1 + (size_t)i * F_,
        enc_ff_w2 + (size_t)i * F_ * D_, WBT ? Wef2 + (size_t)i * F_ * D_ : nullptr,
        enc_ff_b2 + (size_t)i * D_,
        enc_ln2_g + (size_t)i * D_, enc_ln2_b + (size_t)i * D_);
  }

  // ---------------- decoder ----------------
  for (int i = 0; i < L_; ++i) {
    attention(db16, db16,
              dec_sa_qkv_w + (size_t)i * 3 * WQKV, WBT ? Wdsq + (size_t)i * 3 * WQKV : nullptr,
              dec_sa_qkv_b + (size_t)i * 3 * HD_,
              dec_sa_out_w + (size_t)i * HD_ * D_, WBT ? Wdso + (size_t)i * HD_ * D_ : nullptr,
              dec_sa_out_b + (size_t)i * D_,
              dd, db16, 1, dec_ln1_g + (size_t)i * D_, dec_ln1_b + (size_t)i * D_);
    attention(db16, hb16,
              dec_ca_qkv_w + (size_t)i * 3 * WQKV, WBT ? Wdcq + (size_t)i * 3 * WQKV : nullptr,
              dec_ca_qkv_b + (size_t)i * 3 * HD_,
              dec_ca_out_w + (size_t)i * HD_ * D_, WBT ? Wdco + (size_t)i * HD_ * D_ : nullptr,
              dec_ca_out_b + (size_t)i * D_,
              dd, db16, 0, dec_ln2_g + (size_t)i * D_, dec_ln2_b + (size_t)i * D_);
    ffn(dd, db16,
        dec_ff_w1 + (size_t)i * D_ * F_, WBT ? Wdf1 + (size_t)i * D_ * F_ : nullptr,
        dec_ff_b1 + (size_t)i * F_,
        dec_ff_w2 + (size_t)i * F_ * D_, WBT ? Wdf2 + (size_t)i * F_ * D_ : nullptr,
        dec_ff_b2 + (size_t)i * D_,
        dec_ln3_g + (size_t)i * D_, dec_ln3_b + (size_t)i * D_);
  }

  // ---------------- LM head -> f32 logits ----------------
  if (WBT)
    gemm(true, true, false, 0, 0, 0, db16, D_, 0, 0, 0, Whd, D_, 0, 0,
         out, V_, 0, 0, 0, nullptr, -1,
         BT_, V_, D_, 1, 1, 1, 1.0f, head_b, 0);
  else
    gemm(false, true, false, 0, 0, 0, db16, D_, 0, 0, 0, head_w, V_, 0, 0,
         out, V_, 0, 0, 0, nullptr, -1,
         BT_, V_, D_, 1, 1, 1, 1.0f, head_b, 0);
}

// Round 21
// 2128.965 us; speedup vs baseline: 1.0069x; 1.0069x over previous
//
#include <hip/hip_runtime.h>
#include <hip/hip_bf16.h>

#define B_ 2
#define T_ 512
#define D_ 512
#define H_ 8
#define L_ 6
#define F_ 2048
#define V_ 32000
#define BT_ (B_ * T_)
#define HD_ (H_ * D_)
#define BH_ (B_ * H_)

typedef __attribute__((ext_vector_type(8))) short short8;
typedef __attribute__((ext_vector_type(4))) short short4v;
typedef __attribute__((ext_vector_type(4))) float f32x4;

__device__ __forceinline__ short f2b(float f) {
  __hip_bfloat16 h = __float2bfloat16(f);
  short u; __builtin_memcpy(&u, &h, 2); return u;
}
__device__ __forceinline__ float b2f16(short u) {
  return __uint_as_float(((unsigned)(unsigned short)u) << 16);
}
__device__ __forceinline__ void store_c(float* p, float v) { *p = v; }
__device__ __forceinline__ void store_c(short* p, float v) { *p = f2b(v); }

// ------- embedding * sqrt(D) + sinusoidal PE, both streams in one dispatch (y-dim) -------
__global__ __launch_bounds__(256) void embed_kernel(
    const int* __restrict__ tokx, const int* __restrict__ toky,
    const float* __restrict__ emb0, const float* __restrict__ emb1,
    float* __restrict__ out0, float* __restrict__ out1,
    short* __restrict__ o160, short* __restrict__ o161)
{
  const int which = blockIdx.y;
  const int row = blockIdx.x;
  const int t = row & (T_ - 1);
  const int token = which ? toky[row] : tokx[row];
  const float* e = (which ? emb1 : emb0) + (size_t)token * D_;
  float* o = (which ? out1 : out0) + (size_t)row * D_;
  short* o16 = (which ? o161 : o160) + (size_t)row * D_;
  const float scale = sqrtf((float)D_);
  const float nl = -logf(10000.0f);
  for (int d = threadIdx.x; d < D_; d += 256) {
    int i = d >> 1;
    float wl = expf(nl * (2.0f * (float)i) / (float)D_);
    float ang = (float)t * wl;
    float pe = (d & 1) ? cosf(ang) : sinf(ang);
    float v = e[d] * scale + pe;
    o[d] = v; o16[d] = f2b(v);
  }
}

// ------- weight prep: up to 3 tensor groups, f32 [K][N] -> bf16 [N][K], z-partitioned ----
// Block = 64 k-rows x 256 n-cols: reads are 1KB contiguous per row (the limiter per
// r18/r20 A/B); convert inline to bf16; transpose via one bf16 LDS tile (pad 265 ->
// write-phase reads hit 32 banks at 2 lanes/bank). Writes 128B/row (proven irrelevant).
__global__ __launch_bounds__(256) void wconv3_kernel(
    const float* __restrict__ s0, const float* __restrict__ s1, const float* __restrict__ s2,
    short* __restrict__ d0, short* __restrict__ d1, short* __restrict__ d2,
    int K, int N, int zper)
{
  __shared__ unsigned short tb[64][265];
  const int z = blockIdx.z;
  const int grp = z / zper, zi = z - grp * zper;
  const long mstride = (long)K * N;
  const float* src = (grp == 0 ? s0 : grp == 1 ? s1 : s2) + (long)zi * mstride;
  short* dst = (grp == 0 ? d0 : grp == 1 ? d1 : d2) + (long)zi * mstride;
  const int k0 = blockIdx.y * 64, n0 = blockIdx.x * 256;
  const int tid = threadIdx.x;

  // read+convert: 64 k-rows x 256 n, 1KB contiguous per row, 4 rows/iter
  const int rr4 = tid >> 6, c64 = tid & 63;
#pragma unroll
  for (int i = 0; i < 16; ++i) {
    const int kr = i * 4 + rr4;
    float4 v = *(const float4*)(src + (long)(k0 + kr) * N + n0 + c64 * 4);
    tb[kr][c64 * 4 + 0] = (unsigned short)f2b(v.x);
    tb[kr][c64 * 4 + 1] = (unsigned short)f2b(v.y);
    tb[kr][c64 * 4 + 2] = (unsigned short)f2b(v.z);
    tb[kr][c64 * 4 + 3] = (unsigned short)f2b(v.w);
  }
  __syncthreads();
  // write transposed: 256 n-rows x 64 k, 128B contiguous per row, 32 rows/iter
  const int nr = tid >> 3, k8 = (tid & 7) << 3;
#pragma unroll
  for (int i = 0; i < 8; ++i) {
    const int n = i * 32 + nr;
    short8 o;
#pragma unroll
    for (int j = 0; j < 8; ++j) o[j] = (short)tb[k8 + j][n];
    *(short8*)(dst + (long)(n0 + n) * K + k0 + k8) = o;
  }
}

// ---------------- generic MFMA GEMM (r6 structure: single-buffer + reg prefetch) --------
template<bool BTM, typename OutT, int BM>
__global__ __launch_bounds__(256, BM == 64 ? 4 : 3) void mfma_gemm(
    const short* __restrict__ A, long lda, long a_hi, long a_lo, int a_once,
    const void* __restrict__ Bv, long ldb, long b_hi, long b_lo,
    OutT* __restrict__ C, long ldc, long c_hi, long c_lo, long pstride,
    short* __restrict__ Ct, int trans_hh, int relu, int cskip, int cklim,
    int K, int nh, int ksplit, float scale,
    const float* __restrict__ bias, long bias_stride)
{
  constexpr int SA = BM + 1;
  constexpr int AU = BM / 32;
  constexpr int WRN = (BM == 128) ? 2 : 1;
  constexpr int WN  = (BM == 128) ? 64 : 32;
  constexpr int NR  = WN / 16;
  __shared__ short8 As8[8 * SA];
  __shared__ short8 Bs8[8 * 129];
  const int tid = threadIdx.x;
  const int bh = blockIdx.z / ksplit;
  const int kz = blockIdx.z - bh * ksplit;
  const int bb = bh / nh, hh = bh - bb * nh;
  const long a_off = a_once ? (hh >= 1 ? a_lo : 0) : (long)hh * a_lo;
  const short* Ab = A + (long)bb * a_hi + a_off;
  const short* Bbs = (const short*)Bv + (long)bb * b_hi + (long)hh * b_lo;
  const float* Bbf = (const float*)Bv + (long)bb * b_hi + (long)hh * b_lo;
  OutT* Cb = C + (long)bb * c_hi + (long)hh * c_lo + (long)kz * pstride;

  const int gx = gridDim.x, gy = gridDim.y;
  const int nwg = gx * gy;
  int lin = blockIdx.y * gx + blockIdx.x;
  {
    const int xcd = lin & 7, idx = lin >> 3;
    const int q = nwg >> 3, r = nwg & 7;
    lin = (xcd < r ? xcd * (q + 1) : r * (q + 1) + (xcd - r) * q) + idx;
  }
  const int bn = (lin / gy) * 128;
  const int bm = (lin % gy) * BM;
  if (cskip && bn > bm + BM - 1) return;   // causal upper triangle: S never read

  const int klen = K / ksplit, kbase = kz * klen;
  const int lane = tid & 63, wid = tid >> 6;
  const int wr = (WRN == 2) ? (wid >> 1) : 0;
  const int wc = (WRN == 2) ? (wid & 1) : wid;
  const int lg = lane >> 4, r16 = lane & 15;

  int arow[AU], acol[AU];
#pragma unroll
  for (int u = 0; u < AU; ++u) { int o = u * 256 + tid; arow[u] = o >> 3; acol[u] = o & 7; }
  int brow[4], bcol[4];
#pragma unroll
  for (int u = 0; u < 4; ++u) { int o = u * 256 + tid; brow[u] = o >> 3; bcol[u] = o & 7; }
  const int ncol = tid & 127, nsh = tid >> 7;

  short8 pa[AU];
  short8 pbt[4];
  float  pbn[4][8];

  auto load = [&](int k0) {
#pragma unroll
    for (int u = 0; u < AU; ++u)
      pa[u] = *(const short8*)(Ab + (long)(bm + arow[u]) * lda + (k0 + acol[u] * 8));
    if constexpr (BTM) {
#pragma unroll
      for (int u = 0; u < 4; ++u)
        pbt[u] = *(const short8*)(Bbs + (long)(bn + brow[u]) * ldb + (k0 + bcol[u] * 8));
    } else {
      const float* s = Bbf + (long)(k0 + nsh * 32) * ldb + (bn + ncol);
#pragma unroll
      for (int i = 0; i < 4; ++i)
#pragma unroll
        for (int j = 0; j < 8; ++j)
          pbn[i][j] = s[(long)(i * 8 + j) * ldb];
    }
  };
  auto stage = [&]() {
#pragma unroll
    for (int u = 0; u < AU; ++u) As8[acol[u] * SA + arow[u]] = pa[u];
    if constexpr (BTM) {
#pragma unroll
      for (int u = 0; u < 4; ++u) Bs8[bcol[u] * 129 + brow[u]] = pbt[u];
    } else {
#pragma unroll
      for (int i = 0; i < 4; ++i) {
        short8 v;
#pragma unroll
        for (int j = 0; j < 8; ++j) v[j] = f2b(pbn[i][j]);
        Bs8[(nsh * 4 + i) * 129 + ncol] = v;
      }
    }
  };

  f32x4 acc[4][NR] = {};
  auto domfma = [&]() {
#pragma unroll
    for (int kb = 0; kb < 2; ++kb) {
      const int cha = (kb * 4 + lg) * SA;
      const int chb = (kb * 4 + lg) * 129;
      short8 a0 = As8[cha + wr * 64 +  0 + r16];
      short8 a1 = As8[cha + wr * 64 + 16 + r16];
      short8 a2 = As8[cha + wr * 64 + 32 + r16];
      short8 a3 = As8[cha + wr * 64 + 48 + r16];
#pragma unroll
      for (int n = 0; n < NR; ++n) {
        short8 bfr = Bs8[chb + wc * WN + n * 16 + r16];
        acc[0][n] = __builtin_amdgcn_mfma_f32_16x16x32_bf16(a0, bfr, acc[0][n], 0, 0, 0);
        acc[1][n] = __builtin_amdgcn_mfma_f32_16x16x32_bf16(a1, bfr, acc[1][n], 0, 0, 0);
        acc[2][n] = __builtin_amdgcn_mfma_f32_16x16x32_bf16(a2, bfr, acc[2][n], 0, 0, 0);
        acc[3][n] = __builtin_amdgcn_mfma_f32_16x16x32_bf16(a3, bfr, acc[3][n], 0, 0, 0);
      }
    }
  };

  int nsteps = klen >> 6;
  if (cklim) { const int lim = (bm >> 6) + 1; if (lim < nsteps) nsteps = lim; }
  load(kbase);
  stage();
  __syncthreads();
  for (int t = 0; t < nsteps; ++t) {
    const bool more = (t + 1 < nsteps);
    if (more) load(kbase + (t + 1) * 64);
    domfma();
    if (more) { __syncthreads(); stage(); __syncthreads(); }
  }

  const float* bp = bias ? bias + (long)hh * bias_stride : nullptr;
  if (hh == trans_hh) {
#pragma unroll
    for (int m = 0; m < 4; ++m)
#pragma unroll
      for (int n = 0; n < NR; ++n) {
        const int col = bn + wc * WN + n * 16 + r16;
        const float badd = bp ? bp[col] : 0.0f;
        short4v sv;
#pragma unroll
        for (int rr = 0; rr < 4; ++rr) sv[rr] = f2b(acc[m][n][rr] * scale + badd);
        *(short4v*)(Ct + (long)col * BT_ + (bm + wr * 64 + m * 16 + lg * 4)) = sv;
      }
  } else {
#pragma unroll
    for (int m = 0; m < 4; ++m)
#pragma unroll
      for (int rr = 0; rr < 4; ++rr) {
        const int row = bm + wr * 64 + m * 16 + lg * 4 + rr;
        OutT* crow = Cb + (long)row * ldc + bn + wc * WN + r16;
#pragma unroll
        for (int n = 0; n < NR; ++n) {
          float v = acc[m][n][rr] * scale;
          if (bp) v += bp[bn + wc * WN + n * 16 + r16];
          if (relu) v = fmaxf(v, 0.0f);
          store_c(&crow[n * 16], v);
        }
      }
  }
}

// ---- fused: x = resid + bias + sum_z partial; resid(f32) = LN(x)*g+b; + bf16 copy ----
__global__ __launch_bounds__(256) void reduce_ln_kernel(
    const float* __restrict__ P, long pstride, int ks,
    const float* __restrict__ bias, float* __restrict__ hbuf, short* __restrict__ h16,
    const float* __restrict__ gam, const float* __restrict__ bet)
{
  __shared__ float red[256];
  const int row = blockIdx.x, tid = threadIdx.x;
  const long base = (long)row * D_;
  float s0 = hbuf[base + tid] + bias[tid];
  float s1 = hbuf[base + tid + 256] + bias[tid + 256];
  for (int z = 0; z < ks; ++z) {
    s0 += P[(long)z * pstride + base + tid];
    s1 += P[(long)z * pstride + base + tid + 256];
  }
  red[tid] = s0 + s1; __syncthreads();
  for (int o = 128; o > 0; o >>= 1) { if (tid < o) red[tid] += red[tid + o]; __syncthreads(); }
  const float mean = red[0] * (1.0f / D_); __syncthreads();
  const float d0 = s0 - mean, d1 = s1 - mean;
  red[tid] = d0 * d0 + d1 * d1; __syncthreads();
  for (int o = 128; o > 0; o >>= 1) { if (tid < o) red[tid] += red[tid + o]; __syncthreads(); }
  const float inv = rsqrtf(red[0] * (1.0f / D_) + 1e-6f);
  const float v0 = d0 * inv * gam[tid] + bet[tid];
  const float v1 = d1 * inv * gam[tid + 256] + bet[tid + 256];
  hbuf[base + tid] = v0;       h16[base + tid] = f2b(v0);
  hbuf[base + tid + 256] = v1; h16[base + tid + 256] = f2b(v1);
}

// ------- wave-per-row softmax (bf16 S in, bf16 P out); no barriers, no LDS -------
__global__ __launch_bounds__(256) void softmax_kernel(
    const short* __restrict__ S, short* __restrict__ P, int causal)
{
  const int wid = threadIdx.x >> 6, lane = threadIdx.x & 63;
  const int q = blockIdx.x * 4 + wid;
  const int bh = blockIdx.y;
  const short* row = S + ((size_t)bh * T_ + q) * T_;
  short* prow = P + ((size_t)bh * T_ + q) * T_;
  const int n = causal ? (q + 1) : T_;
  const int base = lane * 8;
  short8 sv = *(const short8*)(row + base);
  float vals[8];
#pragma unroll
  for (int j = 0; j < 8; ++j) vals[j] = b2f16(sv[j]);
  float mx = -3.0e38f;
#pragma unroll
  for (int j = 0; j < 8; ++j)
    if (base + j < n) mx = fmaxf(mx, vals[j]);
  mx = fmaxf(mx, __shfl_xor(mx, 1));
  mx = fmaxf(mx, __shfl_xor(mx, 2));
  mx = fmaxf(mx, __shfl_xor(mx, 4));
  mx = fmaxf(mx, __shfl_xor(mx, 8));
  mx = fmaxf(mx, __shfl_xor(mx, 16));
  mx = fmaxf(mx, __shfl_xor(mx, 32));
  float e[8];
  float sm = 0.0f;
#pragma unroll
  for (int j = 0; j < 8; ++j) {
    e[j] = (base + j < n) ? expf(vals[j] - mx) : 0.0f;
    sm += e[j];
  }
  sm += __shfl_xor(sm, 1);
  sm += __shfl_xor(sm, 2);
  sm += __shfl_xor(sm, 4);
  sm += __shfl_xor(sm, 8);
  sm += __shfl_xor(sm, 16);
  sm += __shfl_xor(sm, 32);
  const float inv = 1.0f / sm;
  short8 ov;
#pragma unroll
  for (int j = 0; j < 8; ++j) ov[j] = f2b(e[j] * inv);
  *(short8*)(prow + base) = ov;
}

extern "C" void kernel_launch(void* const* d_in, const int* in_sizes, int n_in,
                              void* d_out, int out_size, void* d_ws, size_t ws_size,
                              hipStream_t stream)
{
  const int*   x         = (const int*)d_in[0];
  const int*   y         = (const int*)d_in[1];
  const float* enc_emb   = (const float*)d_in[2];
  const float* dec_emb   = (const float*)d_in[3];
  const float* enc_qkv_w = (const float*)d_in[4];
  const float* enc_qkv_b = (const float*)d_in[5];
  const float* enc_out_w = (const float*)d_in[6];
  const float* enc_out_b = (const float*)d_in[7];
  const float* enc_ln1_g = (const float*)d_in[8];
  const float* enc_ln1_b = (const float*)d_in[9];
  const float* enc_ff_w1 = (const float*)d_in[10];
  const float* enc_ff_b1 = (const float*)d_in[11];
  const float* enc_ff_w2 = (const float*)d_in[12];
  const float* enc_ff_b2 = (const float*)d_in[13];
  const float* enc_ln2_g = (const float*)d_in[14];
  const float* enc_ln2_b = (const float*)d_in[15];
  const float* dec_sa_qkv_w = (const float*)d_in[16];
  const float* dec_sa_qkv_b = (const float*)d_in[17];
  const float* dec_sa_out_w = (const float*)d_in[18];
  const float* dec_sa_out_b = (const float*)d_in[19];
  const float* dec_ln1_g = (const float*)d_in[20];
  const float* dec_ln1_b = (const float*)d_in[21];
  const float* dec_ca_qkv_w = (const float*)d_in[22];
  const float* dec_ca_qkv_b = (const float*)d_in[23];
  const float* dec_ca_out_w = (const float*)d_in[24];
  const float* dec_ca_out_b = (const float*)d_in[25];
  const float* dec_ln2_g = (const float*)d_in[26];
  const float* dec_ln2_b = (const float*)d_in[27];
  const float* dec_ff_w1 = (const float*)d_in[28];
  const float* dec_ff_b1 = (const float*)d_in[29];
  const float* dec_ff_w2 = (const float*)d_in[30];
  const float* dec_ff_b2 = (const float*)d_in[31];
  const float* dec_ln3_g = (const float*)d_in[32];
  const float* dec_ln3_b = (const float*)d_in[33];
  const float* head_w    = (const float*)d_in[34];
  const float* head_b    = (const float*)d_in[35];
  float* out = (float*)d_out;

  // ---- workspace carve-up ----
  char* wsb = (char*)d_ws;
  size_t off = 0;
  auto carve = [&](size_t bytes) { char* p = wsb + off; off += (bytes + 255) & ~255ull; return p; };
  float* h    = (float*)carve((size_t)BT_ * D_ * 4);
  float* dd   = (float*)carve((size_t)BT_ * D_ * 4);
  short* hb16 = (short*)carve((size_t)BT_ * D_ * 2);
  short* db16 = (short*)carve((size_t)BT_ * D_ * 2);
  short* Qb   = (short*)carve((size_t)BT_ * HD_ * 2);
  short* Kb   = (short*)carve((size_t)BT_ * HD_ * 2);
  short* Vt   = (short*)carve((size_t)HD_ * BT_ * 2);
  float* Sb   = (float*)carve((size_t)BH_ * T_ * T_ * 4);  // split-K partials; S16 aliases head
  short* Pb   = (short*)carve((size_t)BH_ * T_ * T_ * 2);
  short* S16  = (short*)Sb;   // bf16 scores (dead before partials are written)
  short* Ob   = Qb;   // Q dead after QK^T
  short* mid  = Qb;   // attn buffers dead during FFN

  // converted-weight region (bf16 [N][K]); enabled only if workspace fits
  const size_t QKVG = (size_t)L_ * 3 * D_ * HD_;
  const size_t OUTG = (size_t)L_ * HD_ * D_;
  const size_t FFG  = (size_t)L_ * D_ * F_;
  const size_t HEADG = (size_t)D_ * V_;
  const size_t conv_bytes = (3 * QKVG + 3 * OUTG + 2 * FFG + 2 * FFG + HEADG) * 2 + 4096;
  const bool WBT = (ws_size >= off + conv_bytes);
  short *Weq = nullptr, *Wdsq = nullptr, *Wdcq = nullptr;
  short *Weo = nullptr, *Wdso = nullptr, *Wdco = nullptr;
  short *Wef1 = nullptr, *Wef2 = nullptr, *Wdf1 = nullptr, *Wdf2 = nullptr, *Whd = nullptr;
  if (WBT) {
    Weq  = (short*)carve(QKVG * 2);  Wdsq = (short*)carve(QKVG * 2);  Wdcq = (short*)carve(QKVG * 2);
    Weo  = (short*)carve(OUTG * 2);  Wdso = (short*)carve(OUTG * 2);  Wdco = (short*)carve(OUTG * 2);
    Wef1 = (short*)carve(FFG * 2);   Wef2 = (short*)carve(FFG * 2);
    Wdf1 = (short*)carve(FFG * 2);   Wdf2 = (short*)carve(FFG * 2);
    Whd  = (short*)carve(HEADG * 2);
  }

  dim3 blk(256);
  const long TT  = (long)T_ * T_;
  const long THD = (long)T_ * HD_;
  const long WQKV = (long)D_ * HD_;

  if (WBT) {
    // merged weight conversions: 5 dispatches; block = 64k x 256n (1KB read rows)
    wconv3_kernel<<<dim3(HD_/256, D_/64, 3 * 3 * L_), blk, 0, stream>>>(
        enc_qkv_w, dec_sa_qkv_w, dec_ca_qkv_w, Weq, Wdsq, Wdcq, D_, HD_, 3 * L_);
    wconv3_kernel<<<dim3(D_/256, HD_/64, 3 * L_), blk, 0, stream>>>(
        enc_out_w, dec_sa_out_w, dec_ca_out_w, Weo, Wdso, Wdco, HD_, D_, L_);
    wconv3_kernel<<<dim3(F_/256, D_/64, 2 * L_), blk, 0, stream>>>(
        enc_ff_w1, dec_ff_w1, dec_ff_w1, Wef1, Wdf1, Wdf1, D_, F_, L_);
    wconv3_kernel<<<dim3(D_/256, F_/64, 2 * L_), blk, 0, stream>>>(
        enc_ff_w2, dec_ff_w2, dec_ff_w2, Wef2, Wdf2, Wdf2, F_, D_, L_);
    wconv3_kernel<<<dim3(V_/256, D_/64, 1), blk, 0, stream>>>(
        head_w, head_w, head_w, Whd, Whd, Whd, D_, V_, 1);
  }

  auto gemm = [&](bool bt, bool of32, bool bm64, int relu, int cskip, int cklim,
                  const short* A, long lda, long a_hi, long a_lo, int a_once,
                  const void* Bp, long ldb, long b_hi, long b_lo,
                  void* Cp, long ldc, long c_hi, long c_lo, long pstride,
                  short* Ct, int trans_hh,
                  int M, int N, int K, int batch, int nh, int ksplit,
                  float scale, const float* bias, long bstride) {
    dim3 grd(N / 128, M / (bm64 ? 64 : 128), batch * ksplit);
    if (bm64) {
      if (bt) {
        if (of32) mfma_gemm<true , float, 64><<<grd, blk, 0, stream>>>(A, lda, a_hi, a_lo, a_once, Bp, ldb, b_hi, b_lo,
            (float*)Cp, ldc, c_hi, c_lo, pstride, Ct, trans_hh, relu, cskip, cklim, K, nh, ksplit, scale, bias, bstride);
        else      mfma_gemm<true , short, 64><<<grd, blk, 0, stream>>>(A, lda, a_hi, a_lo, a_once, Bp, ldb, b_hi, b_lo,
            (short*)Cp, ldc, c_hi, c_lo, pstride, Ct, trans_hh, relu, cskip, cklim, K, nh, ksplit, scale, bias, bstride);
      } else {
        if (of32) mfma_gemm<false, float, 64><<<grd, blk, 0, stream>>>(A, lda, a_hi, a_lo, a_once, Bp, ldb, b_hi, b_lo,
            (float*)Cp, ldc, c_hi, c_lo, pstride, Ct, trans_hh, relu, cskip, cklim, K, nh, ksplit, scale, bias, bstride);
        else      mfma_gemm<false, short, 64><<<grd, blk, 0, stream>>>(A, lda, a_hi, a_lo, a_once, Bp, ldb, b_hi, b_lo,
            (short*)Cp, ldc, c_hi, c_lo, pstride, Ct, trans_hh, relu, cskip, cklim, K, nh, ksplit, scale, bias, bstride);
      }
    } else {
      if (bt) {
        if (of32) mfma_gemm<true , float, 128><<<grd, blk, 0, stream>>>(A, lda, a_hi, a_lo, a_once, Bp, ldb, b_hi, b_lo,
            (float*)Cp, ldc, c_hi, c_lo, pstride, Ct, trans_hh, relu, cskip, cklim, K, nh, ksplit, scale, bias, bstride);
        else      mfma_gemm<true , short, 128><<<grd, blk, 0, stream>>>(A, lda, a_hi, a_lo, a_once, Bp, ldb, b_hi, b_lo,
            (short*)Cp, ldc, c_hi, c_lo, pstride, Ct, trans_hh, relu, cskip, cklim, K, nh, ksplit, scale, bias, bstride);
      } else {
        if (of32) mfma_gemm<false, float, 128><<<grd, blk, 0, stream>>>(A, lda, a_hi, a_lo, a_once, Bp, ldb, b_hi, b_lo,
            (float*)Cp, ldc, c_hi, c_lo, pstride, Ct, trans_hh, relu, cskip, cklim, K, nh, ksplit, scale, bias, bstride);
        else      mfma_gemm<false, short, 128><<<grd, blk, 0, stream>>>(A, lda, a_hi, a_lo, a_once, Bp, ldb, b_hi, b_lo,
            (short*)Cp, ldc, c_hi, c_lo, pstride, Ct, trans_hh, relu, cskip, cklim, K, nh, ksplit, scale, bias, bstride);
      }
    }
  };

  const int KS = 4;   // split-K for out-proj / FF2

  auto attention = [&](const short* qsrc, const short* kvsrc,
                       const float* qkvw, const short* qkvw16, const float* qkvb,
                       const float* ow, const short* ow16, const float* ob,
                       float* resid, short* resid16, int causal,
                       const float* lng, const float* lnb) {
    // fused Q,K,V (z=3, BM=128); hh=0->Qb, hh=1->Kb, hh=2->Vt^T
    if (WBT)
      gemm(true, false, false, 0, 0, 0, qsrc, D_, 0, (long)(kvsrc - qsrc), 1,
           qkvw16, D_, 0, WQKV,
           Qb, HD_, 0, (long)(Kb - Qb), 0, Vt, 2,
           BT_, HD_, D_, 3, 3, 1, 1.0f, qkvb, HD_);
    else
      gemm(false, false, false, 0, 0, 0, qsrc, D_, 0, (long)(kvsrc - qsrc), 1,
           qkvw, HD_, 0, WQKV,
           Qb, HD_, 0, (long)(Kb - Qb), 0, Vt, 2,
           BT_, HD_, D_, 3, 3, 1, 1.0f, qkvb, HD_);
    // S(bf16) = Q K^T / sqrt(D); causal skips upper-triangle blocks
    gemm(true, false, true, 0, causal, 0, Qb, HD_, THD, D_, 0, Kb, HD_, THD, D_,
         S16, T_, (long)H_ * TT, TT, 0, nullptr, -1,
         T_, T_, D_, BH_, H_, 1, 0.044194173824159216f, nullptr, 0);
    softmax_kernel<<<dim3(T_ / 4, BH_), blk, 0, stream>>>(S16, Pb, causal);
    // O = P V (B = V^T); causal limits K-steps per row-block
    gemm(true, false, true, 0, 0, causal, Pb, T_, (long)H_ * TT, TT, 0,
         Vt, BT_, T_, (long)D_ * BT_,
         Ob, HD_, THD, D_, 0, nullptr, -1,
         T_, D_, T_, BH_, H_, 1, 1.0f, nullptr, 0);
    // out-projection split-K -> f32 partials in Sb; fused reduce+resid+LN
    if (WBT)
      gemm(true, true, true, 0, 0, 0, Ob, HD_, 0, 0, 0, ow16, HD_, 0, 0,
           Sb, D_, 0, 0, (long)BT_ * D_, nullptr, -1,
           BT_, D_, HD_, 1, 1, KS, 1.0f, nullptr, 0);
    else
      gemm(false, true, true, 0, 0, 0, Ob, HD_, 0, 0, 0, ow, D_, 0, 0,
           Sb, D_, 0, 0, (long)BT_ * D_, nullptr, -1,
           BT_, D_, HD_, 1, 1, KS, 1.0f, nullptr, 0);
    reduce_ln_kernel<<<dim3(BT_), blk, 0, stream>>>(
        Sb, (long)BT_ * D_, KS, ob, resid, resid16, lng, lnb);
  };

  auto ffn = [&](float* resid, short* resid16,
                 const float* w1, const short* w116, const float* b1,
                 const float* w2, const short* w216, const float* b2,
                 const float* lng, const float* lnb) {
    if (WBT)
      gemm(true, false, true, 1, 0, 0, resid16, D_, 0, 0, 0, w116, D_, 0, 0,
           mid, F_, 0, 0, 0, nullptr, -1,
           BT_, F_, D_, 1, 1, 1, 1.0f, b1, 0);
    else
      gemm(false, false, true, 1, 0, 0, resid16, D_, 0, 0, 0, w1, F_, 0, 0,
           mid, F_, 0, 0, 0, nullptr, -1,
           BT_, F_, D_, 1, 1, 1, 1.0f, b1, 0);
    if (WBT)
      gemm(true, true, true, 0, 0, 0, mid, F_, 0, 0, 0, w216, F_, 0, 0,
           Sb, D_, 0, 0, (long)BT_ * D_, nullptr, -1,
           BT_, D_, F_, 1, 1, KS, 1.0f, nullptr, 0);
    else
      gemm(false, true, true, 0, 0, 0, mid, F_, 0, 0, 0, w2, D_, 0, 0,
           Sb, D_, 0, 0, (long)BT_ * D_, nullptr, -1,
           BT_, D_, F_, 1, 1, KS, 1.0f, nullptr, 0);
    reduce_ln_kernel<<<dim3(BT_), blk, 0, stream>>>(
        Sb, (long)BT_ * D_, KS, b2, resid, resid16, lng, lnb);
  };

  // ---------------- embeddings (both streams, one dispatch) ----------------
  embed_kernel<<<dim3(BT_, 2), blk, 0, stream>>>(x, y, enc_emb, dec_emb, h, dd, hb16, db16);

  // ---------------- encoder ----------------
  for (int i = 0; i < L_; ++i) {
    attention(hb16, hb16,
              enc_qkv_w + (size_t)i * 3 * WQKV, WBT ? Weq + (size_t)i * 3 * WQKV : nullptr,
              enc_qkv_b + (size_t)i * 3 * HD_,
              enc_out_w + (size_t)i * HD_ * D_, WBT ? Weo + (size_t)i * HD_ * D_ : nullptr,
              enc_out_b + (size_t)i * D_,
              h, hb16, 0, enc_ln1_g + (size_t)i * D_, enc_ln1_b + (size_t)i * D_);
    ffn(h, hb16,
        enc_ff_w1 + (size_t)i * D_ * F_, WBT ? Wef1 + (size_t)i * D_ * F_ : nullptr,
        enc_ff_b1 + (size_t)i * F_,
        enc_ff_w2 + (size_t)i * F_ * D_, WBT ? Wef2 + (size_t)i * F_ * D_ : nullptr,
        enc_ff_b2 + (size_t)i * D_,
        enc_ln2_g + (size_t)i * D_, enc_ln2_b + (size_t)i * D_);
  }

  // ---------------- decoder ----------------
  for (int i = 0; i < L_; ++i) {
    attention(db16, db16,
              dec_sa_qkv_w + (size_t)i * 3 * WQKV, WBT ? Wdsq + (size_t)i * 3 * WQKV : nullptr,
              dec_sa_qkv_b + (size_t)i * 3 * HD_,
              dec_sa_out_w + (size_t)i * HD_ * D_, WBT ? Wdso + (size_t)i * HD_ * D_ : nullptr,
              dec_sa_out_b + (size_t)i * D_,
              dd, db16, 1, dec_ln1_g + (size_t)i * D_, dec_ln1_b + (size_t)i * D_);
    attention(db16, hb16,
              dec_ca_qkv_w + (size_t)i * 3 * WQKV, WBT ? Wdcq + (size_t)i * 3 * WQKV : nullptr,
              dec_ca_qkv_b + (size_t)i * 3 * HD_,
              dec_ca_out_w + (size_t)i * HD_ * D_, WBT ? Wdco + (size_t)i * HD_ * D_ : nullptr,
              dec_ca_out_b + (size_t)i * D_,
              dd, db16, 0, dec_ln2_g + (size_t)i * D_, dec_ln2_b + (size_t)i * D_);
    ffn(dd, db16,
        dec_ff_w1 + (size_t)i * D_ * F_, WBT ? Wdf1 + (size_t)i * D_ * F_ : nullptr,
        dec_ff_b1 + (size_t)i * F_,
        dec_ff_w2 + (size_t)i * F_ * D_, WBT ? Wdf2 + (size_t)i * F_ * D_ : nullptr,
        dec_ff_b2 + (size_t)i * D_,
        dec_ln3_g + (size_t)i * D_, dec_ln3_b + (size_t)i * D_);
  }

  // ---------------- LM head -> f32 logits ----------------
  if (WBT)
    gemm(true, true, false, 0, 0, 0, db16, D_, 0, 0, 0, Whd, D_, 0, 0,
         out, V_, 0, 0, 0, nullptr, -1,
         BT_, V_, D_, 1, 1, 1, 1.0f, head_b, 0);
  else
    gemm(false, true, false, 0, 0, 0, db16, D_, 0, 0, 0, head_w, V_, 0, 0,
         out, V_, 0, 0, 0, nullptr, -1,
         BT_, V_, D_, 1, 1, 1, 1.0f, head_b, 0);
}